// Round 9
// baseline (33.085 us; speedup 1.0000x reference)
//
#include <hip/hip_runtime.h>
#include <math.h>

#define NUM_ENTITY 100000
#define NUM_TYPE   5000
#define DIM        128
#define BATCH      512
#define MARGIN     2.0f

#define TG 64   // types per wave (one per lane)
#define BG 8    // batch rows per wave

typedef _Float16 half_t;
typedef half_t half2_t __attribute__((ext_vector_type(2)));

// r8 falsified the VGPR theory (unroll-2 + cap: zero delta). r6->r7 showed
// compute savings land 1:1 -> the residual ~17us is ADDITIVE block overhead:
// per-block staging chains, 3 barriers x 4-wave convoys, LDS reduce.
// This design removes the categories: 1-wave blocks (no barriers), t-rows
// register-resident (no LDS for t, loaded once per wave), e via a 2KB LDS
// tile read back with wave-uniform BROADCAST addresses (conflict-free by
// definition), no reduction phase. 5056 waves (~4.9/SIMD), ~96 VGPR -> all
// resident. Per-wave ~1900 instr -> VALU-serial floor ~7.8us.
__device__ __forceinline__ uint32_t pk2(float x, float y) {
    return __builtin_bit_cast(uint32_t, __builtin_amdgcn_cvt_pkrtz(x, y));
}

__device__ __forceinline__ float absdot(uint32_t eu, uint32_t tu, float acc) {
    const half2_t ones = {(half_t)1.0f, (half_t)1.0f};
    half2_t d = __builtin_bit_cast(half2_t, eu) - __builtin_bit_cast(half2_t, tu);
    const uint32_t du = __builtin_bit_cast(uint32_t, d) & 0x7fff7fffu;
#if __has_builtin(__builtin_amdgcn_fdot2)
    return __builtin_amdgcn_fdot2(__builtin_bit_cast(half2_t, du), ones, acc, false);
#else
    half2_t a = __builtin_bit_cast(half2_t, du);
    return acc + (float)a[0] + (float)a[1];
#endif
}

__global__ __launch_bounds__(64) void l1dist_sigmoid_kernel(
    const float* __restrict__ ent,
    const float* __restrict__ typ,
    const int*   __restrict__ xb,
    float*       __restrict__ out)
{
    __shared__ uint32_t eL[BG * 64];   // 8 rows x 64 dwords (128 f16) = 2 KB

    const int l  = threadIdx.x;        // 0..63
    const int t0 = blockIdx.x * TG;
    const int b0 = blockIdx.y * BG;

    // ---- stage e rows f32->f16 cooperatively: 8 rows x 32 float4, 4/lane
#pragma unroll
    for (int s = 0; s < 4; ++s) {
        const int g   = l + 64 * s;    // 0..255
        const int row = g >> 5;        // 32 float4 per row
        const int c4  = g & 31;
        const int er  = xb[b0 + row];
        const float4 v = *(const float4*)&ent[er * DIM + c4 * 4];
        uint2 w;
        w.x = pk2(v.x, v.y);
        w.y = pk2(v.z, v.w);
        *(uint2*)&eL[row * 64 + c4 * 2] = w;
    }

    // ---- own type row -> registers as packed f16 (64 dwords)
    const int tl = min(t0 + l, NUM_TYPE - 1);
    uint4 tf[16];
#pragma unroll
    for (int c = 0; c < 16; ++c) {
        const float4 a = *(const float4*)&typ[tl * DIM + 8 * c];
        const float4 b = *(const float4*)&typ[tl * DIM + 8 * c + 4];
        tf[c].x = pk2(a.x, a.y);
        tf[c].y = pk2(a.z, a.w);
        tf[c].z = pk2(b.x, b.y);
        tf[c].w = pk2(b.z, b.w);
    }

    __syncthreads();   // single-wave block: effectively just a waitcnt

    const bool valid = (t0 + l) < NUM_TYPE;

    // ---- compute: 8 b-rows; e read as wave-uniform broadcast b128
#pragma unroll 1
    for (int i = 0; i < BG; ++i) {
        float acc = 0.0f;
#pragma unroll
        for (int c = 0; c < 16; ++c) {
            const uint4 ev = *(const uint4*)&eL[i * 64 + c * 4];
            acc = absdot(ev.x, tf[c].x, acc);
            acc = absdot(ev.y, tf[c].y, acc);
            acc = absdot(ev.z, tf[c].z, acc);
            acc = absdot(ev.w, tf[c].w, acc);
        }
        if (valid) {
            const float x = MARGIN - acc;
            out[(b0 + i) * NUM_TYPE + t0 + l] = 1.0f / (1.0f + __expf(-x));
        }
    }
}

extern "C" void kernel_launch(void* const* d_in, const int* in_sizes, int n_in,
                              void* d_out, int out_size, void* d_ws, size_t ws_size,
                              hipStream_t stream) {
    const float* ent = (const float*)d_in[0];
    const float* typ = (const float*)d_in[1];
    const int*   xb  = (const int*)d_in[2];
    float*       out = (float*)d_out;

    dim3 grid((NUM_TYPE + TG - 1) / TG, BATCH / BG);  // (79, 64) = 5056 one-wave blocks
    dim3 block(64);
    l1dist_sigmoid_kernel<<<grid, block, 0, stream>>>(ent, typ, xb, out);
}